// Round 1
// baseline (28692.831 us; speedup 1.0000x reference)
//
#include <hip/hip_runtime.h>
#include <math.h>

// ESN forward: x_{t+1} = 0.1*x_t + 0.9*tanh(W_in @ u_t + W @ x_t); y_t = Wout @ x_{t+1}
// W sparse (5%) -> padded ELL held in REGISTERS. 64 cooperative WGs.
// R5: flag+payload exchange. Producer: relaxed agent stores of 64 plain floats,
// then one RELEASE flag/WG (wave-level vmcnt covers data). Consumer: relaxed spin
// on its 2 producer flags, one acquire fence (buffer_inv -> L1/L2 dropped), then
// cached float4 payload loads. Static operands (ELL/Win/Wout slices) pinned in
// VGPRs so the per-step cache invalidation costs nothing.

#define NX 4096
#define NU 128
#define NY 64
#define TSTEPS 4096
#define CAP 352            // padded nnz per row (mean 204.8, sd 13.9)
#define WGS 64
#define TPB 512
#define RPW (NX / WGS)     // 64 rows per workgroup
#define TPR (TPB / RPW)    // 8 threads per row
#define EPT (CAP / TPR)    // 44 ELL entries per thread (contiguous chunk)
#define UPT (NU / TPR)     // 16 W_in entries per thread (contiguous chunk)

typedef unsigned int u32;

// --- Kernel 1: deterministic dense->ELL compaction, one block per row ---
// Also zeroes the 64 step flags (must be re-zeroed every launch: re-runs would
// otherwise see stale flags >= t and read garbage).
__global__ void build_ell_kernel(const float* __restrict__ W, int2* __restrict__ ell,
                                 u32* __restrict__ flags) {
    const int r = blockIdx.x;
    const int tid = threadIdx.x;
    if (r == 0 && tid < WGS) flags[tid] = 0;
    const int wv = tid >> 6, ln = tid & 63;
    __shared__ int wave_tot[4];
    __shared__ int base;
    if (tid == 0) base = 0;
    __syncthreads();
    const float* row = W + (size_t)r * NX;
    int2* out = ell + (size_t)r * CAP;
    for (int chunk = 0; chunk < NX; chunk += 256) {
        float w = row[chunk + tid];
        bool p = (w != 0.0f);
        unsigned long long m = __ballot(p);
        int lp = (int)__popcll(m & ((1ull << ln) - 1ull));
        if (ln == 63) wave_tot[wv] = lp + (p ? 1 : 0);
        __syncthreads();
        int wbase = 0;
        #pragma unroll
        for (int i = 0; i < 4; ++i)
            if (i < wv) wbase += wave_tot[i];
        int tot = wave_tot[0] + wave_tot[1] + wave_tot[2] + wave_tot[3];
        if (p) {
            int o = base + wbase + lp;
            if (o < CAP) out[o] = make_int2(chunk + tid, __float_as_int(w));
        }
        __syncthreads();
        if (tid == 0) base += tot;
        __syncthreads();
    }
    // zero-pad remainder: col=0, val=0 contributes exactly 0
    for (int o = base + tid; o < CAP; o += 256) out[o] = make_int2(0, 0);
}

// --- Kernel 2: cooperative sequential recurrence, flag + cached payload ---
__global__ void __launch_bounds__(TPB, 2) esn_kernel(
    const float* __restrict__ UT, const float* __restrict__ x0,
    const float* __restrict__ Win, const float* __restrict__ Wout,
    const int2* __restrict__ ell, float* __restrict__ xbuf,  // [2][NX] plain floats
    u32* __restrict__ flags,                                 // [WGS]
    float* __restrict__ Y)
{
    __shared__ __align__(16) float xl[2][NX];
    __shared__ float xnew_l[RPW];
    __shared__ float red[TPB / 64];

    const int tid = threadIdx.x;
    const int wg  = blockIdx.x;              // 0..63
    const int grp = tid >> 3;                // row group within WG (0..63)
    const int ln  = tid & 7;                 // lane within row group
    const int r   = wg * RPW + grp;          // global row this 8-thread group owns

    // ---- pin static per-thread operand slices in VGPRs (acquire fence kills
    //      L1/L2 every step; registers are the only safe home) ----
    int4 er[EPT / 2];                        // 22 x int4 = 88 VGPR (two (col,val) pairs each)
    {
        const int4* ellrow = (const int4*)(ell + (size_t)r * CAP + ln * EPT);
        #pragma unroll
        for (int i = 0; i < EPT / 2; ++i) er[i] = ellrow[i];
    }
    float4 wreg_in[UPT / 4];                 // 16 VGPR: Win[r, ln*16 .. +16)
    {
        const float4* winrow = (const float4*)(Win + (size_t)r * NU + ln * UPT);
        #pragma unroll
        for (int i = 0; i < UPT / 4; ++i) wreg_in[i] = winrow[i];
    }
    float wreg_out[NX / TPB];                // 8 VGPR: Wout[wg, tid::512]
    {
        const float* woutrow = Wout + (size_t)wg * NX;
        #pragma unroll
        for (int i = 0; i < NX / TPB; ++i) wreg_out[i] = woutrow[tid + i * TPB];
    }

    // producers of the two float4s this thread stages (float4 k comes from WG k/16)
    const u32 f0 = (u32)(tid >> 4);          // 0..31
    const u32 f1 = f0 + (TPB >> 4);          // 32..63

    for (int t = 0; t < TSTEPS; ++t) {
        float* xc = xl[t & 1];

        // ---- x-independent partial: acc = Win[r,:] @ u_t (issued before spin) ----
        float acc = 0.0f;
        {
            const float4* u4 = (const float4*)(UT + (size_t)t * NU + ln * UPT);
            #pragma unroll
            for (int i = 0; i < UPT / 4; ++i) {
                float4 u = u4[i];
                acc += wreg_in[i].x * u.x + wreg_in[i].y * u.y
                     + wreg_in[i].z * u.z + wreg_in[i].w * u.w;
            }
        }

        // ---- stage x_t into LDS ----
        if (t == 0) {
            const float4* xs4 = (const float4*)x0;
            ((float4*)xc)[tid]       = xs4[tid];
            ((float4*)xc)[tid + TPB] = xs4[tid + TPB];
        } else {
            // spin only on this thread's two producers; start staging early
            while (__hip_atomic_load(flags + f0, __ATOMIC_RELAXED, __HIP_MEMORY_SCOPE_AGENT) < (u32)t ||
                   __hip_atomic_load(flags + f1, __ATOMIC_RELAXED, __HIP_MEMORY_SCOPE_AGENT) < (u32)t) { }
            __builtin_amdgcn_fence(__ATOMIC_ACQUIRE, "agent");   // waitcnt + buffer_inv
            const float4* xs4 = (const float4*)(xbuf + (size_t)(t & 1) * NX);
            ((float4*)xc)[tid]       = xs4[tid];
            ((float4*)xc)[tid + TPB] = xs4[tid + TPB];
        }
        __syncthreads();

        // ---- acc += W[r,:] @ x_t (register-resident ELL, LDS gather) ----
        #pragma unroll
        for (int i = 0; i < EPT / 2; ++i) {
            acc += __int_as_float(er[i].y) * xc[er[i].x]
                 + __int_as_float(er[i].w) * xc[er[i].z];
        }
        acc += __shfl_down(acc, 4, 8);
        acc += __shfl_down(acc, 2, 8);
        acc += __shfl_down(acc, 1, 8);
        if (ln == 0)
            xnew_l[grp] = 0.1f * xc[r] + 0.9f * tanhf(acc);
        __syncthreads();

        // ---- publish x_{t+1}: wave 0 stores 64 plain floats (relaxed agent,
        //      write-through), then tid 0 RELEASE-stores the flag. The release's
        //      s_waitcnt vmcnt(0) covers wave 0's own data stores. ----
        if (tid < RPW)
            __hip_atomic_store(xbuf + (size_t)((t + 1) & 1) * NX + wg * RPW + tid,
                               xnew_l[tid], __ATOMIC_RELAXED, __HIP_MEMORY_SCOPE_AGENT);
        if (tid == 0)
            __hip_atomic_store(flags + wg, (u32)(t + 1),
                               __ATOMIC_RELEASE, __HIP_MEMORY_SCOPE_AGENT);

        // ---- readout Y[t-1] = Wout[wg] . x_t (overlaps flag/data propagation) ----
        if (t > 0) {
            float a = 0.0f;
            #pragma unroll
            for (int i = 0; i < NX / TPB; ++i) a += wreg_out[i] * xc[tid + i * TPB];
            for (int off = 32; off; off >>= 1) a += __shfl_down(a, off, 64);
            if ((tid & 63) == 0) red[tid >> 6] = a;
            __syncthreads();
            if (tid == 0) {
                float s = 0.0f;
                #pragma unroll
                for (int i = 0; i < TPB / 64; ++i) s += red[i];
                Y[(size_t)(t - 1) * NY + wg] = s;
            }
        }
    }

    // ---- final: wait for x_T (flags == TSTEPS, buffer 0), then Y[T-1] ----
    {
        float* xc = xl[0];
        while (__hip_atomic_load(flags + f0, __ATOMIC_RELAXED, __HIP_MEMORY_SCOPE_AGENT) < (u32)TSTEPS ||
               __hip_atomic_load(flags + f1, __ATOMIC_RELAXED, __HIP_MEMORY_SCOPE_AGENT) < (u32)TSTEPS) { }
        __builtin_amdgcn_fence(__ATOMIC_ACQUIRE, "agent");
        const float4* xs4 = (const float4*)(xbuf + (size_t)(TSTEPS & 1) * NX);
        ((float4*)xc)[tid]       = xs4[tid];
        ((float4*)xc)[tid + TPB] = xs4[tid + TPB];
        __syncthreads();

        float a = 0.0f;
        #pragma unroll
        for (int i = 0; i < NX / TPB; ++i) a += wreg_out[i] * xc[tid + i * TPB];
        for (int off = 32; off; off >>= 1) a += __shfl_down(a, off, 64);
        if ((tid & 63) == 0) red[tid >> 6] = a;
        __syncthreads();
        if (tid == 0) {
            float s = 0.0f;
            #pragma unroll
            for (int i = 0; i < TPB / 64; ++i) s += red[i];
            Y[(size_t)(TSTEPS - 1) * NY + wg] = s;
        }
    }
}

extern "C" void kernel_launch(void* const* d_in, const int* in_sizes, int n_in,
                              void* d_out, int out_size, void* d_ws, size_t ws_size,
                              hipStream_t stream) {
    const float* UT   = (const float*)d_in[0];  // [T, NU]
    const float* x0   = (const float*)d_in[1];  // [NX]
    const float* Win  = (const float*)d_in[2];  // [NX, NU]
    const float* W    = (const float*)d_in[3];  // [NX, NX]
    const float* Wout = (const float*)d_in[4];  // [NY, NX]
    float* Y = (float*)d_out;                   // [T*NY]

    char* ws = (char*)d_ws;
    float* xbuf = (float*)ws;                   // 2*NX floats = 32 KB
    u32*  flags = (u32*)(ws + 32768);           // 64 step flags
    int2* ell   = (int2*)(ws + 65536);          // NX*CAP*8 = 11,534,336 B

    build_ell_kernel<<<dim3(NX), dim3(256), 0, stream>>>(W, ell, flags);

    void* args[] = { (void*)&UT, (void*)&x0, (void*)&Win, (void*)&Wout,
                     (void*)&ell, (void*)&xbuf, (void*)&flags, (void*)&Y };
    hipLaunchCooperativeKernel((const void*)esn_kernel, dim3(WGS), dim3(TPB),
                               args, 0, stream);
}

// Round 2
// 19344.817 us; speedup vs baseline: 1.4832x; 1.4832x over previous
//
#include <hip/hip_runtime.h>
#include <math.h>

// ESN forward: x_{t+1} = 0.1*x_t + 0.9*tanh(W_in @ u_t + W @ x_t); y_t = Wout @ x_{t+1}
// W sparse (5%) -> padded ELL in ws (L2-resident). 64 cooperative WGs.
// R6: R4's fence-free epoch-in-data exchange, contention-reduced.
//  - exchange words remapped so each consumer thread's 8 words are one 64B line
//    from ONE producer WG -> spin on a 4B relaxed hint flag (16x less MALL
//    traffic than R4's 64B/round), then a single validated data round.
//  - hint flags carry NO ordering semantics: the (epoch<<32|fbits) packed data
//    words remain the only correctness gate. No fences anywhere -> ELL/UT/Win
//    stay L1/L2-cached (the R5 regression was the per-step buffer_inv).
//  - rows publish directly from their ln==0 thread right after tanh (earlier,
//    staggered stores cut producer tail skew); the Y-readout barrier doubles
//    as the flag-store barrier, so still 2 barriers/step.

#define NX 4096
#define NU 128
#define NY 64
#define TSTEPS 4096
#define CAP 336            // padded nnz per row (mean 204.8, sd 13.9; 336 = +9.4 sd)
#define WGS 64
#define TPB 512
#define RPW (NX / WGS)     // 64 rows per workgroup
#define TPR (TPB / RPW)    // 8 threads per row
#define EPT (CAP / TPR)    // 42 ELL entries per thread (contiguous chunk)
#define UPT (NU / TPR)     // 16 W_in entries per thread (contiguous chunk)
#define WPT (NX / TPB)     // 8 packed words staged per thread (contiguous)

typedef unsigned long long u64;
typedef unsigned int u32;

// --- Kernel 1: deterministic dense->ELL compaction, one block per row ---
// Also zeroes the 64 hint flags (benign even if stale, but keep them clean).
__global__ void build_ell_kernel(const float* __restrict__ W, int2* __restrict__ ell,
                                 u32* __restrict__ flags) {
    const int r = blockIdx.x;
    const int tid = threadIdx.x;
    if (r == 0 && tid < WGS) flags[tid] = 0;
    const int wv = tid >> 6, ln = tid & 63;
    __shared__ int wave_tot[4];
    __shared__ int base;
    if (tid == 0) base = 0;
    __syncthreads();
    const float* row = W + (size_t)r * NX;
    int2* out = ell + (size_t)r * CAP;
    for (int chunk = 0; chunk < NX; chunk += 256) {
        float w = row[chunk + tid];
        bool p = (w != 0.0f);
        unsigned long long m = __ballot(p);
        int lp = (int)__popcll(m & ((1ull << ln) - 1ull));
        if (ln == 63) wave_tot[wv] = lp + (p ? 1 : 0);
        __syncthreads();
        int wbase = 0;
        #pragma unroll
        for (int i = 0; i < 4; ++i)
            if (i < wv) wbase += wave_tot[i];
        int tot = wave_tot[0] + wave_tot[1] + wave_tot[2] + wave_tot[3];
        if (p) {
            int o = base + wbase + lp;
            if (o < CAP) out[o] = make_int2(chunk + tid, __float_as_int(w));
        }
        __syncthreads();
        if (tid == 0) base += tot;
        __syncthreads();
    }
    // zero-pad remainder: col=0, val=0 contributes exactly 0
    for (int o = base + tid; o < CAP; o += 256) out[o] = make_int2(0, 0);
}

// --- Kernel 2: cooperative sequential recurrence ---
__global__ void __launch_bounds__(TPB, 1) esn_kernel(
    const float* __restrict__ UT, const float* __restrict__ x0,
    const float* __restrict__ Win, const float* __restrict__ Wout,
    const int2* __restrict__ ell, u64* __restrict__ xbuf,  // [2][NX] packed epoch|val
    u32* __restrict__ flags,                               // [WGS] hint only
    float* __restrict__ Y)
{
    __shared__ __align__(16) float xl[2][NX];
    __shared__ float red[TPB / 64];

    const int tid = threadIdx.x;
    const int wg  = blockIdx.x;              // 0..63
    const int grp = tid >> 3;                // row group within WG (0..63)
    const int ln  = tid & 7;                 // lane within row group
    const int r   = wg * RPW + grp;          // global row this 8-thread group owns
    const int pf  = tid >> 3;                // producer WG of this thread's 8 words

    // static per-thread slices; ELL stays a cached global pointer (L2-hot, no fences)
    const int4* ellrow = (const int4*)(ell + (size_t)r * CAP + ln * EPT);
    float4 wreg_in[UPT / 4];                 // Win[r, ln*16 .. +16) pinned
    {
        const float4* winrow = (const float4*)(Win + (size_t)r * NU + ln * UPT);
        #pragma unroll
        for (int i = 0; i < UPT / 4; ++i) wreg_in[i] = winrow[i];
    }
    float wreg_out[WPT];                     // Wout[wg, tid::512] pinned
    {
        const float* woutrow = Wout + (size_t)wg * NX;
        #pragma unroll
        for (int i = 0; i < WPT; ++i) wreg_out[i] = woutrow[tid + i * TPB];
    }

    for (int t = 0; t < TSTEPS; ++t) {
        float* xc = xl[t & 1];

        // ---- x-independent partial: acc = Win[r,:] @ u_t (issued before spin) ----
        float acc = 0.0f;
        {
            const float4* u4 = (const float4*)(UT + (size_t)t * NU + ln * UPT);
            #pragma unroll
            for (int i = 0; i < UPT / 4; ++i) {
                float4 u = u4[i];
                acc += wreg_in[i].x * u.x + wreg_in[i].y * u.y
                     + wreg_in[i].z * u.z + wreg_in[i].w * u.w;
            }
        }

        // ---- stage x_t into LDS ----
        if (t == 0) {
            const float4* xs4 = (const float4*)x0;
            float4* xl4 = (float4*)xc;
            xl4[tid]       = xs4[tid];
            xl4[tid + TPB] = xs4[tid + TPB];
        } else {
            // cheap spin: one 4B relaxed hint (no ordering semantics)
            while (__hip_atomic_load(flags + pf, __ATOMIC_RELAXED,
                                     __HIP_MEMORY_SCOPE_AGENT) < (u32)t) { }
            // validated data round: 8 packed words, one 64B line, one producer
            const u64* xs = xbuf + (size_t)(t & 1) * NX + (size_t)tid * WPT;
            u64 v[WPT];
            bool ok;
            do {
                ok = true;
                #pragma unroll
                for (int j = 0; j < WPT; ++j)
                    v[j] = __hip_atomic_load(xs + j, __ATOMIC_RELAXED,
                                             __HIP_MEMORY_SCOPE_AGENT);
                #pragma unroll
                for (int j = 0; j < WPT; ++j)
                    ok &= ((u32)(v[j] >> 32) == (u32)t);
            } while (!ok);
            float4 lo = make_float4(__uint_as_float((u32)v[0]), __uint_as_float((u32)v[1]),
                                    __uint_as_float((u32)v[2]), __uint_as_float((u32)v[3]));
            float4 hi = make_float4(__uint_as_float((u32)v[4]), __uint_as_float((u32)v[5]),
                                    __uint_as_float((u32)v[6]), __uint_as_float((u32)v[7]));
            float4* dst = (float4*)(xc + (size_t)tid * WPT);
            dst[0] = lo;
            dst[1] = hi;
        }
        __syncthreads();

        // ---- acc += W[r,:] @ x_t (ELL gather from LDS, L2-cached index/val) ----
        #pragma unroll
        for (int i = 0; i < EPT / 2; ++i) {
            int4 cv = ellrow[i];   // two (col,val) pairs
            acc += __int_as_float(cv.y) * xc[cv.x]
                 + __int_as_float(cv.w) * xc[cv.z];
        }
        acc += __shfl_down(acc, 4, 8);
        acc += __shfl_down(acc, 2, 8);
        acc += __shfl_down(acc, 1, 8);

        // ---- publish x_{t+1} immediately: one packed 8B store per row ----
        if (ln == 0) {
            float xnew = 0.1f * xc[r] + 0.9f * tanhf(acc);
            u64 packed = ((u64)(u32)(t + 1) << 32) | (u64)__float_as_uint(xnew);
            __hip_atomic_store(xbuf + (size_t)((t + 1) & 1) * NX + r, packed,
                               __ATOMIC_RELAXED, __HIP_MEMORY_SCOPE_AGENT);
        }

        // ---- readout Y[t-1] = Wout[wg] . x_t; barrier doubles as flag gate ----
        if (t > 0) {
            float a = 0.0f;
            #pragma unroll
            for (int i = 0; i < WPT; ++i) a += wreg_out[i] * xc[tid + i * TPB];
            for (int off = 32; off; off >>= 1) a += __shfl_down(a, off, 64);
            if ((tid & 63) == 0) red[tid >> 6] = a;
        }
        __syncthreads();   // all publishes issued before this point
        if (tid == 0) {
            __hip_atomic_store(flags + wg, (u32)(t + 1),
                               __ATOMIC_RELAXED, __HIP_MEMORY_SCOPE_AGENT);
            if (t > 0) {
                float s = 0.0f;
                #pragma unroll
                for (int i = 0; i < TPB / 64; ++i) s += red[i];
                Y[(size_t)(t - 1) * NY + wg] = s;
            }
        }
    }

    // ---- final: stage x_T (epoch TSTEPS, buffer 0), then Y[T-1] ----
    {
        float* xc = xl[0];
        while (__hip_atomic_load(flags + pf, __ATOMIC_RELAXED,
                                 __HIP_MEMORY_SCOPE_AGENT) < (u32)TSTEPS) { }
        const u64* xs = xbuf + (size_t)(TSTEPS & 1) * NX + (size_t)tid * WPT;
        u64 v[WPT];
        bool ok;
        do {
            ok = true;
            #pragma unroll
            for (int j = 0; j < WPT; ++j)
                v[j] = __hip_atomic_load(xs + j, __ATOMIC_RELAXED,
                                         __HIP_MEMORY_SCOPE_AGENT);
            #pragma unroll
            for (int j = 0; j < WPT; ++j)
                ok &= ((u32)(v[j] >> 32) == (u32)TSTEPS);
        } while (!ok);
        #pragma unroll
        for (int j = 0; j < WPT; ++j)
            xc[tid * WPT + j] = __uint_as_float((u32)v[j]);
        __syncthreads();

        float a = 0.0f;
        #pragma unroll
        for (int i = 0; i < WPT; ++i) a += wreg_out[i] * xc[tid + i * TPB];
        for (int off = 32; off; off >>= 1) a += __shfl_down(a, off, 64);
        if ((tid & 63) == 0) red[tid >> 6] = a;
        __syncthreads();
        if (tid == 0) {
            float s = 0.0f;
            #pragma unroll
            for (int i = 0; i < TPB / 64; ++i) s += red[i];
            Y[(size_t)(TSTEPS - 1) * NY + wg] = s;
        }
    }
}

extern "C" void kernel_launch(void* const* d_in, const int* in_sizes, int n_in,
                              void* d_out, int out_size, void* d_ws, size_t ws_size,
                              hipStream_t stream) {
    const float* UT   = (const float*)d_in[0];  // [T, NU]
    const float* x0   = (const float*)d_in[1];  // [NX]
    const float* Win  = (const float*)d_in[2];  // [NX, NU]
    const float* W    = (const float*)d_in[3];  // [NX, NX]
    const float* Wout = (const float*)d_in[4];  // [NY, NX]
    float* Y = (float*)d_out;                   // [T*NY]

    char* ws = (char*)d_ws;
    u64*  xbuf  = (u64*)ws;                     // 2*NX packed words = 64 KB
    u32*  flags = (u32*)(ws + 65536);           // 64 hint flags
    int2* ell   = (int2*)(ws + 69632);          // NX*CAP*8 = 11,010,048 B

    build_ell_kernel<<<dim3(NX), dim3(256), 0, stream>>>(W, ell, flags);

    void* args[] = { (void*)&UT, (void*)&x0, (void*)&Win, (void*)&Wout,
                     (void*)&ell, (void*)&xbuf, (void*)&flags, (void*)&Y };
    hipLaunchCooperativeKernel((const void*)esn_kernel, dim3(WGS), dim3(TPB),
                               args, 0, stream);
}